// Round 11
// baseline (92.190 us; speedup 1.0000x reference)
//
#include <hip/hip_runtime.h>
#include <hip/hip_bf16.h>

#define NROWS 8192
#define DEMB 256
#define MARGIN 0.2f
#define NCLS 512
#define TPC 8                    // B tiles (128 cols) per chunk
#define NSTEP 16                 // 8 tiles * 2 half-K steps (BK=128)
#define MCAP 64                  // max class size (mean 16, 12 sigma)

typedef __attribute__((ext_vector_type(4))) float f32x4;
typedef __attribute__((ext_vector_type(8))) short bf16x8;

static __device__ __forceinline__ unsigned short f2b(float f) {
    unsigned u = __builtin_bit_cast(unsigned, f);
    u += 0x7fffu + ((u >> 16) & 1u);           // RNE round to bf16
    return (unsigned short)(u >> 16);
}
static __device__ __forceinline__ float b2f(unsigned short b) {
    unsigned u = ((unsigned)b) << 16;
    return __builtin_bit_cast(float, u);
}
// order-preserving f32 -> u32 encode (max-compatible; finite values never encode to 0)
static __device__ __forceinline__ unsigned encf(float f) {
    unsigned u = __builtin_bit_cast(unsigned, f);
    return (u & 0x80000000u) ? ~u : (u | 0x80000000u);
}
static __device__ __forceinline__ float decf(unsigned e) {
    unsigned u = (e & 0x80000000u) ? (e ^ 0x80000000u) : ~e;
    return __builtin_bit_cast(float, u);
}
static __device__ __forceinline__ void gload16(const void* g, void* l) {
    __builtin_amdgcn_global_load_lds(
        (const __attribute__((address_space(1))) unsigned int*)g,
        (__attribute__((address_space(3))) unsigned int*)l, 16, 0, 0);
}

// K1: row-L2-normalize fp32 -> bf16; zero amax; bucket rows by class.
__global__ __launch_bounds__(256) void k_norm(const float* __restrict__ x,
                                              const int* __restrict__ labels,
                                              unsigned short* __restrict__ xnb,
                                              unsigned* __restrict__ amax,
                                              int* __restrict__ bcnt,
                                              int* __restrict__ mem) {
    int gid = blockIdx.x * blockDim.x + threadIdx.x;
    if (gid < NROWS) {
        amax[gid] = 0u;
        int l = labels[gid];
        int slot = atomicAdd(&bcnt[l], 1);
        if (slot < MCAP) mem[l * MCAP + slot] = gid;
    }
    int row  = gid >> 6;
    int lane = threadIdx.x & 63;
    const float4* p = reinterpret_cast<const float4*>(x + (size_t)row * DEMB) + lane;
    float4 v = *p;
    float s = v.x * v.x + v.y * v.y + v.z * v.z + v.w * v.w;
#pragma unroll
    for (int m = 1; m < 64; m <<= 1) s += __shfl_xor(s, m);
    float inv = 1.0f / fmaxf(sqrtf(s), 1e-8f);
    ushort4 o;
    o.x = f2b(v.x * inv); o.y = f2b(v.y * inv);
    o.z = f2b(v.z * inv); o.w = f2b(v.w * inv);
    *(reinterpret_cast<ushort4*>(xnb + (size_t)row * DEMB) + lane) = o;
}

// K2: strip-streaming MFMA row-max (VERBATIM round-8 kernel: 47.2us proven).
// Grid (64 strips, 8 chunks), 512 threads. A-strip fragments in registers;
// B streamed through 16-step double-buffered LDS pipeline (XOR-swizzled).
// Row-max accumulated in registers; one atomicMax set per block at the end.
__global__ __launch_bounds__(512, 2) void k_maxneg(const unsigned short* __restrict__ xnb,
                                                   const int* __restrict__ labels,
                                                   unsigned* __restrict__ amax) {
    extern __shared__ char lds[];
    unsigned short* Bl = (unsigned short*)lds;   // dbuf: 2 x 32KB

    int tid  = threadIdx.x;
    int wid  = tid >> 6, lane = tid & 63;
    int wr   = wid >> 1, wc = wid & 1;           // 4 row-subwaves x 2 col-subwaves
    int arow = lane & 15, kgrp = lane >> 4;

    int i0 = blockIdx.x * 128;
    int j0 = blockIdx.y * (TPC * 128);

    // Hoist A fragments: row = i0 + wr*32 + m*16 + arow, k = kk*32 + kgrp*8
    bf16x8 a[2][8];
    const unsigned short* ap0 = xnb + (size_t)(i0 + wr * 32 + arow) * DEMB + kgrp * 8;
#pragma unroll
    for (int m = 0; m < 2; ++m)
#pragma unroll
        for (int kk = 0; kk < 8; ++kk)
            a[m][kk] = *(const bf16x8*)(ap0 + m * 16 * DEMB + kk * 32);

    int rlab[2][4];
#pragma unroll
    for (int m = 0; m < 2; ++m)
#pragma unroll
        for (int r = 0; r < 4; ++r)
            rlab[m][r] = labels[i0 + wr * 32 + m * 16 + kgrp * 4 + r];

    float rmax[2][4] = {{-1e30f, -1e30f, -1e30f, -1e30f},
                        {-1e30f, -1e30f, -1e30f, -1e30f}};
    f32x4 acc[2][4] = {};

    // stage B half-tile: tile t, k-half h -> 128 rows x 128 k-cols = 32KB
    auto stage = [&](int buf, int t, int h) {
#pragma unroll
        for (int is = 0; is < 4; ++is) {
            int idx  = is * 512 + tid;                  // 16B chunk id 0..2047
            int row  = idx >> 4;                        // 16 chunks per 256B row
            int colb = (idx & 15) << 4;
            int scol = (colb ^ ((row & 15) << 4)) >> 1; // pre-swizzled elem col
            const unsigned short* src =
                xnb + (size_t)(j0 + t * 128 + row) * DEMB + h * 128 + scol;
            unsigned short* dst = Bl + buf * 16384 + is * 4096 + wid * 512;
            gload16(src, dst);
        }
    };

    int clab[4], nlab[4];
    stage(0, 0, 0);
#pragma unroll
    for (int n = 0; n < 4; ++n) clab[n] = labels[j0 + wc * 64 + n * 16 + arow];

    int sw = arow << 4;
    for (int s = 0; s < NSTEP; ++s) {
        __syncthreads();                                 // buf[s&1] ready
        if (s + 1 < NSTEP) stage((s + 1) & 1, (s + 1) >> 1, (s + 1) & 1);
        int tile = s >> 1, h = s & 1;
        if (h == 0 && tile + 1 < TPC) {
#pragma unroll
            for (int n = 0; n < 4; ++n)
                nlab[n] = labels[j0 + (tile + 1) * 128 + wc * 64 + n * 16 + arow];
        }
        const char* Bt = (const char*)(Bl + (s & 1) * 16384);
        bf16x8 b[4][4];
#pragma unroll
        for (int n = 0; n < 4; ++n) {
            int rb = (wc * 64 + n * 16 + arow) * 256;
#pragma unroll
            for (int ksl = 0; ksl < 4; ++ksl)
                b[n][ksl] = *(const bf16x8*)(Bt + rb + ((ksl * 64 + kgrp * 16) ^ sw));
        }
#pragma unroll
        for (int m = 0; m < 2; ++m)
#pragma unroll
            for (int n = 0; n < 4; ++n)
#pragma unroll
                for (int ksl = 0; ksl < 4; ++ksl)
                    acc[m][n] = __builtin_amdgcn_mfma_f32_16x16x32_bf16(
                        a[m][h * 4 + ksl], b[n][ksl], acc[m][n], 0, 0, 0);
        if (h == 1) {                                    // tile done: masked fold
#pragma unroll
            for (int m = 0; m < 2; ++m)
#pragma unroll
                for (int r = 0; r < 4; ++r) {
                    float v = rmax[m][r];
                    int rl = rlab[m][r];
#pragma unroll
                    for (int n = 0; n < 4; ++n)
                        if (clab[n] != rl) v = fmaxf(v, acc[m][n][r]);
                    rmax[m][r] = v;
                }
#pragma unroll
            for (int m = 0; m < 2; ++m)
#pragma unroll
                for (int n = 0; n < 4; ++n) acc[m][n] = (f32x4){0.f, 0.f, 0.f, 0.f};
#pragma unroll
            for (int n = 0; n < 4; ++n) clab[n] = nlab[n];
        }
    }

    // Reduce over 16 col-lanes, combine wc pair via LDS, one atomic per row.
    float* smax = (float*)Bl;                            // [2][128] in buf0 (dead)
#pragma unroll
    for (int m = 0; m < 2; ++m)
#pragma unroll
        for (int r = 0; r < 4; ++r) {
            float v = rmax[m][r];
#pragma unroll
            for (int msk = 1; msk < 16; msk <<= 1) v = fmaxf(v, __shfl_xor(v, msk));
            if (arow == 0) smax[wc * 128 + wr * 32 + m * 16 + kgrp * 4 + r] = v;
        }
    __syncthreads();
    if (tid < 128) {
        float v = fmaxf(smax[tid], smax[128 + tid]);
        if (v > -1e29f) atomicMax(amax + i0 + tid, encf(v));
    }
}

// K3: STAGELESS per-class pair losses + fused finalize. No row staging, no
// gather barriers: 16-lane groups read both pair rows straight from L2
// (xnb is L2/L3-resident). Tiny LDS -> all 512 blocks concurrent.
__global__ __launch_bounds__(256) void k_cpairs3(const unsigned short* __restrict__ xnb,
                                                 const unsigned* __restrict__ amax,
                                                 const int* __restrict__ bcnt,
                                                 const int* __restrict__ mem,
                                                 float* __restrict__ gsum,
                                                 int* __restrict__ gcnt,
                                                 unsigned* __restrict__ done,
                                                 float* __restrict__ out) {
    __shared__ float slloss[16];
    __shared__ int slcnt[16];

    int c   = blockIdx.x;
    int tid = threadIdx.x;
    int nc  = bcnt[c];
    if (nc > MCAP) nc = MCAP;
    const int* cm = mem + c * MCAP;

    int slot = tid >> 4, gl = tid & 15;
    int npairs = nc * (nc - 1) / 2;
    float gloss = 0.f;
    int gc = 0;
    for (int p = slot; p < npairs; p += 16) {
        int i = 0, rem = p;
        while (rem >= nc - 1 - i) { rem -= nc - 1 - i; ++i; }
        int j = i + 1 + rem;
        int gi = cm[i], gj = cm[j];
        const bf16x8* ra = (const bf16x8*)(xnb + (size_t)gi * DEMB) + gl * 2;
        const bf16x8* rb = (const bf16x8*)(xnb + (size_t)gj * DEMB) + gl * 2;
        bf16x8 a0 = ra[0], a1 = ra[1];
        bf16x8 b0 = rb[0], b1 = rb[1];
        float dot = 0.f;
#pragma unroll
        for (int e = 0; e < 8; ++e) {
            dot += b2f((unsigned short)a0[e]) * b2f((unsigned short)b0[e]);
            dot += b2f((unsigned short)a1[e]) * b2f((unsigned short)b1[e]);
        }
#pragma unroll
        for (int msk = 1; msk < 16; msk <<= 1) dot += __shfl_xor(dot, msk);
        if (gl == 0) {
            int ga = (gi < gj) ? gi : gj;                // anchor = min global idx
            unsigned e = amax[ga];
            if (e != 0u) {                               // has_neg(anchor)
                float sdm = 1.0f - decf(e);
                gloss += fmaxf(1.0f - dot - sdm + MARGIN, 0.0f);
                gc += 1;
            }
        }
    }
    if (gl == 0) { slloss[slot] = gloss; slcnt[slot] = gc; }
    __syncthreads();
    if (tid == 0) {
        float s = 0.f; int k = 0;
        for (int q = 0; q < 16; ++q) { s += slloss[q]; k += slcnt[q]; }
        atomicAdd(gsum, s);
        atomicAdd(gcnt, k);
        __threadfence();
        unsigned old = atomicAdd(done, 1u);
        if (old == NCLS - 1) {                   // last block finalizes
            float S = atomicAdd(gsum, 0.0f);
            int   K = atomicAdd(gcnt, 0);
            out[0] = (K > 0) ? S / (float)K : 0.0f;
            out[1] = (float)K;
        }
    }
}

extern "C" void kernel_launch(void* const* d_in, const int* in_sizes, int n_in,
                              void* d_out, int out_size, void* d_ws, size_t ws_size,
                              hipStream_t stream) {
    const float* emb  = (const float*)d_in[0];
    const int* labels = (const int*)d_in[1];
    float* out = (float*)d_out;

    char* ws = (char*)d_ws;
    unsigned short* xnb = (unsigned short*)ws;                            // 4 MB
    unsigned* amax = (unsigned*)(ws + (size_t)4 * 1024 * 1024);           // 32 KB
    int*      bcnt = (int*)     (ws + (size_t)4 * 1024 * 1024 + 32768);   // 2048 B
    float*    gsum = (float*)   (ws + (size_t)4 * 1024 * 1024 + 34816);   // 4 B
    int*      gcnt = (int*)     (ws + (size_t)4 * 1024 * 1024 + 34820);   // 4 B
    unsigned* done = (unsigned*)(ws + (size_t)4 * 1024 * 1024 + 34824);   // 4 B
    int*      mem  = (int*)     (ws + (size_t)4 * 1024 * 1024 + 36864);   // 128 KB

    hipMemsetAsync(bcnt, 0, 2048 + 16, stream);          // bcnt + gsum/gcnt/done
    k_norm<<<NROWS / 4, 256, 0, stream>>>(emb, labels, xnb, amax, bcnt, mem);
    dim3 g2(NROWS / 128, NCLS / 64);   // 64 strips x 8 chunks
    k_maxneg<<<g2, 512, 65536, stream>>>(xnb, labels, amax);
    k_cpairs3<<<NCLS, 256, 0, stream>>>(xnb, amax, bcnt, mem, gsum, gcnt, done, out);
}

// Round 13
// 83.425 us; speedup vs baseline: 1.1051x; 1.1051x over previous
//
#include <hip/hip_runtime.h>
#include <hip/hip_bf16.h>

#define NROWS 8192
#define DEMB 256
#define MARGIN 0.2f
#define NCLS 512
#define TPC 8                    // B tiles (128 cols) per chunk
#define NSTEP 16                 // 8 tiles * 2 half-K steps (BK=128)
#define MCAP 64                  // max class size (mean 16, 12 sigma)
#define SROW 264                 // padded LDS row stride (ushorts) for k_cpairs2

typedef __attribute__((ext_vector_type(4))) float f32x4;
typedef __attribute__((ext_vector_type(8))) short bf16x8;

static __device__ __forceinline__ unsigned short f2b(float f) {
    unsigned u = __builtin_bit_cast(unsigned, f);
    u += 0x7fffu + ((u >> 16) & 1u);           // RNE round to bf16
    return (unsigned short)(u >> 16);
}
static __device__ __forceinline__ float b2f(unsigned short b) {
    unsigned u = ((unsigned)b) << 16;
    return __builtin_bit_cast(float, u);
}
// order-preserving f32 -> u32 encode (max-compatible; finite values never encode to 0)
static __device__ __forceinline__ unsigned encf(float f) {
    unsigned u = __builtin_bit_cast(unsigned, f);
    return (u & 0x80000000u) ? ~u : (u | 0x80000000u);
}
static __device__ __forceinline__ float decf(unsigned e) {
    unsigned u = (e & 0x80000000u) ? (e ^ 0x80000000u) : ~e;
    return __builtin_bit_cast(float, u);
}
static __device__ __forceinline__ void gload16(const void* g, void* l) {
    __builtin_amdgcn_global_load_lds(
        (const __attribute__((address_space(1))) unsigned int*)g,
        (__attribute__((address_space(3))) unsigned int*)l, 16, 0, 0);
}

// K1: row-L2-normalize fp32 -> bf16; zero amax; bucket rows by class.
// (bcnt pre-zeroed by the memset node.)
__global__ __launch_bounds__(256) void k_norm(const float* __restrict__ x,
                                              const int* __restrict__ labels,
                                              unsigned short* __restrict__ xnb,
                                              unsigned* __restrict__ amax,
                                              int* __restrict__ bcnt,
                                              int* __restrict__ mem) {
    int gid = blockIdx.x * blockDim.x + threadIdx.x;
    if (gid < NROWS) {
        int l = labels[gid];
        int slot = atomicAdd(&bcnt[l], 1);
        if (slot < MCAP) mem[l * MCAP + slot] = gid;
    }
    int row  = gid >> 6;
    int lane = threadIdx.x & 63;
    const float4* p = reinterpret_cast<const float4*>(x + (size_t)row * DEMB) + lane;
    float4 v = *p;
    float s = v.x * v.x + v.y * v.y + v.z * v.z + v.w * v.w;
#pragma unroll
    for (int m = 1; m < 64; m <<= 1) s += __shfl_xor(s, m);
    float inv = 1.0f / fmaxf(sqrtf(s), 1e-8f);
    ushort4 o;
    o.x = f2b(v.x * inv); o.y = f2b(v.y * inv);
    o.z = f2b(v.z * inv); o.w = f2b(v.w * inv);
    *(reinterpret_cast<ushort4*>(xnb + (size_t)row * DEMB) + lane) = o;
}

// K2: strip-streaming MFMA row-max (VERBATIM round-8 kernel: 47.2us, 3x repro).
// Grid (64 strips, 8 chunks), 512 threads. A-strip fragments in registers;
// B streamed through 16-step double-buffered LDS pipeline (XOR-swizzled).
// Row-max accumulated in registers; one atomicMax set per block at the end.
__global__ __launch_bounds__(512, 2) void k_maxneg(const unsigned short* __restrict__ xnb,
                                                   const int* __restrict__ labels,
                                                   unsigned* __restrict__ amax) {
    extern __shared__ char lds[];
    unsigned short* Bl = (unsigned short*)lds;   // dbuf: 2 x 32KB

    int tid  = threadIdx.x;
    int wid  = tid >> 6, lane = tid & 63;
    int wr   = wid >> 1, wc = wid & 1;           // 4 row-subwaves x 2 col-subwaves
    int arow = lane & 15, kgrp = lane >> 4;

    int i0 = blockIdx.x * 128;
    int j0 = blockIdx.y * (TPC * 128);

    // Hoist A fragments: row = i0 + wr*32 + m*16 + arow, k = kk*32 + kgrp*8
    bf16x8 a[2][8];
    const unsigned short* ap0 = xnb + (size_t)(i0 + wr * 32 + arow) * DEMB + kgrp * 8;
#pragma unroll
    for (int m = 0; m < 2; ++m)
#pragma unroll
        for (int kk = 0; kk < 8; ++kk)
            a[m][kk] = *(const bf16x8*)(ap0 + m * 16 * DEMB + kk * 32);

    int rlab[2][4];
#pragma unroll
    for (int m = 0; m < 2; ++m)
#pragma unroll
        for (int r = 0; r < 4; ++r)
            rlab[m][r] = labels[i0 + wr * 32 + m * 16 + kgrp * 4 + r];

    float rmax[2][4] = {{-1e30f, -1e30f, -1e30f, -1e30f},
                        {-1e30f, -1e30f, -1e30f, -1e30f}};
    f32x4 acc[2][4] = {};

    // stage B half-tile: tile t, k-half h -> 128 rows x 128 k-cols = 32KB
    auto stage = [&](int buf, int t, int h) {
#pragma unroll
        for (int is = 0; is < 4; ++is) {
            int idx  = is * 512 + tid;                  // 16B chunk id 0..2047
            int row  = idx >> 4;                        // 16 chunks per 256B row
            int colb = (idx & 15) << 4;
            int scol = (colb ^ ((row & 15) << 4)) >> 1; // pre-swizzled elem col
            const unsigned short* src =
                xnb + (size_t)(j0 + t * 128 + row) * DEMB + h * 128 + scol;
            unsigned short* dst = Bl + buf * 16384 + is * 4096 + wid * 512;
            gload16(src, dst);
        }
    };

    int clab[4], nlab[4];
    stage(0, 0, 0);
#pragma unroll
    for (int n = 0; n < 4; ++n) clab[n] = labels[j0 + wc * 64 + n * 16 + arow];

    int sw = arow << 4;
    for (int s = 0; s < NSTEP; ++s) {
        __syncthreads();                                 // buf[s&1] ready
        if (s + 1 < NSTEP) stage((s + 1) & 1, (s + 1) >> 1, (s + 1) & 1);
        int tile = s >> 1, h = s & 1;
        if (h == 0 && tile + 1 < TPC) {
#pragma unroll
            for (int n = 0; n < 4; ++n)
                nlab[n] = labels[j0 + (tile + 1) * 128 + wc * 64 + n * 16 + arow];
        }
        const char* Bt = (const char*)(Bl + (s & 1) * 16384);
        bf16x8 b[4][4];
#pragma unroll
        for (int n = 0; n < 4; ++n) {
            int rb = (wc * 64 + n * 16 + arow) * 256;
#pragma unroll
            for (int ksl = 0; ksl < 4; ++ksl)
                b[n][ksl] = *(const bf16x8*)(Bt + rb + ((ksl * 64 + kgrp * 16) ^ sw));
        }
#pragma unroll
        for (int m = 0; m < 2; ++m)
#pragma unroll
            for (int n = 0; n < 4; ++n)
#pragma unroll
                for (int ksl = 0; ksl < 4; ++ksl)
                    acc[m][n] = __builtin_amdgcn_mfma_f32_16x16x32_bf16(
                        a[m][h * 4 + ksl], b[n][ksl], acc[m][n], 0, 0, 0);
        if (h == 1) {                                    // tile done: masked fold
#pragma unroll
            for (int m = 0; m < 2; ++m)
#pragma unroll
                for (int r = 0; r < 4; ++r) {
                    float v = rmax[m][r];
                    int rl = rlab[m][r];
#pragma unroll
                    for (int n = 0; n < 4; ++n)
                        if (clab[n] != rl) v = fmaxf(v, acc[m][n][r]);
                    rmax[m][r] = v;
                }
#pragma unroll
            for (int m = 0; m < 2; ++m)
#pragma unroll
                for (int n = 0; n < 4; ++n) acc[m][n] = (f32x4){0.f, 0.f, 0.f, 0.f};
#pragma unroll
            for (int n = 0; n < 4; ++n) clab[n] = nlab[n];
        }
    }

    // Reduce over 16 col-lanes, combine wc pair via LDS, one atomic per row.
    float* smax = (float*)Bl;                            // [2][128] in buf0 (dead)
#pragma unroll
    for (int m = 0; m < 2; ++m)
#pragma unroll
        for (int r = 0; r < 4; ++r) {
            float v = rmax[m][r];
#pragma unroll
            for (int msk = 1; msk < 16; msk <<= 1) v = fmaxf(v, __shfl_xor(v, msk));
            if (arow == 0) smax[wc * 128 + wr * 32 + m * 16 + kgrp * 4 + r] = v;
        }
    __syncthreads();
    if (tid < 128) {
        float v = fmaxf(smax[tid], smax[128 + tid]);
        if (v > -1e29f) atomicMax(amax + i0 + tid, encf(v));
    }
}

// K3: per-class pair losses (r8 staged body) + fused last-block finalize.
__global__ __launch_bounds__(256) void k_cpairs2(const unsigned short* __restrict__ xnb,
                                                 const unsigned* __restrict__ amax,
                                                 const int* __restrict__ bcnt,
                                                 const int* __restrict__ mem,
                                                 float* __restrict__ gsum,
                                                 int* __restrict__ gcnt,
                                                 unsigned* __restrict__ done,
                                                 float* __restrict__ out) {
    __shared__ unsigned short srows[MCAP * SROW];        // ~33.8 KB, padded stride
    __shared__ int mlist[MCAP];
    __shared__ float sdm[MCAP];
    __shared__ unsigned char shn[MCAP];
    __shared__ float slloss[16];
    __shared__ int slcnt[16];

    int c   = blockIdx.x;
    int tid = threadIdx.x;
    int nc  = bcnt[c];
    if (nc > MCAP) nc = MCAP;

    if (tid < nc) {
        int gi = mem[c * MCAP + tid];
        mlist[tid] = gi;
        unsigned e = amax[gi];
        shn[tid] = (e != 0u);
        sdm[tid] = 1.0f - decf(e);
    }
    __syncthreads();
    int nch = nc * 32;                                   // 16B chunks per class
    for (int ch = tid; ch < nch; ch += 256) {
        int r = ch >> 5, cc = ch & 31;
        *(bf16x8*)(srows + r * SROW + cc * 8) =
            *(const bf16x8*)(xnb + (size_t)mlist[r] * DEMB + cc * 8);
    }
    __syncthreads();

    int slot = tid >> 4, gl = tid & 15;
    int npairs = nc * (nc - 1) / 2;
    float gloss = 0.f;
    int gc = 0;
    for (int p = slot; p < npairs; p += 16) {
        int i = 0, rem = p;
        while (rem >= nc - 1 - i) { rem -= nc - 1 - i; ++i; }
        int j = i + 1 + rem;
        bf16x8 a0 = *(const bf16x8*)(srows + i * SROW + gl * 16);
        bf16x8 a1 = *(const bf16x8*)(srows + i * SROW + gl * 16 + 8);
        bf16x8 b0 = *(const bf16x8*)(srows + j * SROW + gl * 16);
        bf16x8 b1 = *(const bf16x8*)(srows + j * SROW + gl * 16 + 8);
        float dot = 0.f;
#pragma unroll
        for (int e = 0; e < 8; ++e) {
            dot += b2f((unsigned short)a0[e]) * b2f((unsigned short)b0[e]);
            dot += b2f((unsigned short)a1[e]) * b2f((unsigned short)b1[e]);
        }
#pragma unroll
        for (int msk = 1; msk < 16; msk <<= 1) dot += __shfl_xor(dot, msk);
        if (gl == 0) {
            int ai = (mlist[i] < mlist[j]) ? i : j;      // anchor = min global idx
            if (shn[ai]) {
                gloss += fmaxf(1.0f - dot - sdm[ai] + MARGIN, 0.0f);
                gc += 1;
            }
        }
    }
    if (gl == 0) { slloss[slot] = gloss; slcnt[slot] = gc; }
    __syncthreads();
    if (tid == 0) {
        float s = 0.f; int k = 0;
        for (int q = 0; q < 16; ++q) { s += slloss[q]; k += slcnt[q]; }
        atomicAdd(gsum, s);
        atomicAdd(gcnt, k);
        __threadfence();
        unsigned old = atomicAdd(done, 1u);
        if (old == NCLS - 1) {                           // last block finalizes
            float S = atomicAdd(gsum, 0.0f);
            int   K = atomicAdd(gcnt, 0);
            out[0] = (K > 0) ? S / (float)K : 0.0f;
            out[1] = (float)K;
        }
    }
}

extern "C" void kernel_launch(void* const* d_in, const int* in_sizes, int n_in,
                              void* d_out, int out_size, void* d_ws, size_t ws_size,
                              hipStream_t stream) {
    const float* emb  = (const float*)d_in[0];
    const int* labels = (const int*)d_in[1];
    float* out = (float*)d_out;

    char* ws = (char*)d_ws;
    unsigned short* xnb = (unsigned short*)ws;                            // 4 MB
    unsigned* amax = (unsigned*)(ws + (size_t)4 * 1024 * 1024);           // 32 KB
    int*      bcnt = (int*)     (ws + (size_t)4 * 1024 * 1024 + 32768);   // 2048 B
    float*    gsum = (float*)   (ws + (size_t)4 * 1024 * 1024 + 34816);   // 4 B
    int*      gcnt = (int*)     (ws + (size_t)4 * 1024 * 1024 + 34820);   // 4 B
    unsigned* done = (unsigned*)(ws + (size_t)4 * 1024 * 1024 + 34824);   // 4 B
    int*      mem  = (int*)     (ws + (size_t)4 * 1024 * 1024 + 36864);   // 128 KB

    // one memset: amax (32KB) + bcnt (2KB) + gsum/gcnt/done (12B), contiguous
    hipMemsetAsync(amax, 0, 32768 + 2048 + 12, stream);
    k_norm<<<NROWS / 4, 256, 0, stream>>>(emb, labels, xnb, amax, bcnt, mem);
    dim3 g2(NROWS / 128, NCLS / 64);   // 64 strips x 8 chunks
    k_maxneg<<<g2, 512, 65536, stream>>>(xnb, labels, amax);
    k_cpairs2<<<NCLS, 256, 0, stream>>>(xnb, amax, bcnt, mem, gsum, gcnt, done, out);
}